// Round 11
// baseline (245.926 us; speedup 1.0000x reference)
//
#include <hip/hip_runtime.h>
#include <hip/hip_bf16.h>

#define IN_C 512
#define HID_C 256
#define OUT_C 64

typedef __attribute__((ext_vector_type(8))) short bf16x8;
typedef __attribute__((ext_vector_type(4))) float f32x4;
typedef __attribute__((ext_vector_type(2))) float f32x2;

__device__ __forceinline__ ushort f2bf(float f) {
  __hip_bfloat16 h = __float2bfloat16(f);
  union { __hip_bfloat16 h; ushort u; } v; v.h = h; return v.u;
}
__device__ __forceinline__ uint pack2bf(float a, float b) {
  return (uint)f2bf(a) | ((uint)f2bf(b) << 16);
}
__device__ __forceinline__ float u2f(uint u) {
  union { uint i; float f; } v; v.i = u; return v.f;
}
// packed accumulate of 4 bf16 {lo0,hi0,lo1,hi1} in (ux,uy) — exact bf16 values.
__device__ __forceinline__ void pkacc(f32x2& aLo, f32x2& aHi, uint ux, uint uy) {
  f32x2 lo, hi;
  lo[0] = u2f(ux << 16);         lo[1] = u2f(uy << 16);
  hi[0] = u2f(ux & 0xffff0000u); hi[1] = u2f(uy & 0xffff0000u);
  aLo += lo;   // v_pk_add_f32
  aHi += hi;
}
// async global->LDS, 16B per lane. LDS dest must be linear (base + lane*16).
__device__ __forceinline__ void glds16(const ushort* g, ushort* l) {
  __builtin_amdgcn_global_load_lds(
      (const __attribute__((address_space(1))) unsigned int*)(const void*)g,
      (__attribute__((address_space(3))) unsigned int*)(void*)l, 16, 0, 0);
}

// ---------------- graph preprocessing ----------------

// edges blocks: deg count atomics. Extra 256 blocks: W1/W2 transpose (fp32 -> bf16, n-major).
__global__ void deg_count_tw(const int* __restrict__ dst, int* __restrict__ counts, int E, int eb,
                             const float* __restrict__ W1, ushort* __restrict__ W1t,
                             const float* __restrict__ W2, ushort* __restrict__ W2t) {
  if ((int)blockIdx.x < eb) {
    int e = blockIdx.x * 256 + threadIdx.x;
    if (e < E) atomicAdd(&counts[dst[e]], 1);
    return;
  }
  int b2 = blockIdx.x - eb;
  int z = b2 >> 7;        // 0: W1, 1: W2
  int rem = b2 & 127;
  int bx = rem & 7, by = rem >> 3;
  const float* W; ushort* Wt; int K, N;
  if (z == 0) { W = W1; Wt = W1t; K = IN_C; N = HID_C; }
  else        { W = W2; Wt = W2t; K = HID_C; N = OUT_C; }
  int n0 = bx * 32, k0 = by * 32;
  if (n0 >= N || k0 >= K) return;
  __shared__ ushort t[32][33];
  int tx = threadIdx.x & 31;
  int ty = threadIdx.x >> 5;  // 0..7
#pragma unroll
  for (int i = 0; i < 4; ++i) {
    int k = k0 + ty + i * 8;
    t[ty + i * 8][tx] = f2bf(W[(size_t)k * N + n0 + tx]);
  }
  __syncthreads();
#pragma unroll
  for (int i = 0; i < 4; ++i) {
    int n = n0 + ty + i * 8;
    Wt[(size_t)n * K + k0 + tx] = t[tx][ty + i * 8];
  }
}

#define SCAN_TILE 1024

__global__ __launch_bounds__(256) void scan_block_sums(const int* __restrict__ counts,
                                                       int* __restrict__ partial, int n) {
  int base = blockIdx.x * SCAN_TILE + threadIdx.x * 4;
  int s = 0;
  if (base + 3 < n) {
    int4 v = *(const int4*)(counts + base);
    s = v.x + v.y + v.z + v.w;
  } else {
#pragma unroll
    for (int i = 0; i < 4; ++i) if (base + i < n) s += counts[base + i];
  }
#pragma unroll
  for (int off = 1; off < 64; off <<= 1) s += __shfl_xor(s, off);
  __shared__ int ws[4];
  int lane = threadIdx.x & 63, wid = threadIdx.x >> 6;
  if (lane == 0) ws[wid] = s;
  __syncthreads();
  if (threadIdx.x == 0) partial[blockIdx.x] = ws[0] + ws[1] + ws[2] + ws[3];
}

// intra-block exclusive scan; block base = sum of partial[0..bid-1] (nb<=64, one wave).
__global__ __launch_bounds__(256) void scan_write(const int* __restrict__ counts,
                                                  const int* __restrict__ partial,
                                                  int* __restrict__ offs,
                                                  int* __restrict__ cur,
                                                  float* __restrict__ dinv,
                                                  int n, int E, int nb) {
  __shared__ int sbase;
  int tid = threadIdx.x;
  if (tid < 64) {
    int v = (tid < (int)blockIdx.x && tid < nb) ? partial[tid] : 0;
#pragma unroll
    for (int off = 1; off < 64; off <<= 1) v += __shfl_xor(v, off);
    if (tid == 0) sbase = v;
  }
  __syncthreads();
  int pbase = sbase;
  int base = blockIdx.x * SCAN_TILE + tid * 4;
  int4 c = make_int4(0, 0, 0, 0);
  if (base + 3 < n) {
    c = *(const int4*)(counts + base);
  } else {
    if (base + 0 < n) c.x = counts[base + 0];
    if (base + 1 < n) c.y = counts[base + 1];
    if (base + 2 < n) c.z = counts[base + 2];
  }
  int tsum = c.x + c.y + c.z + c.w;
  int lane = tid & 63, wid = tid >> 6;
  int incl = tsum;
#pragma unroll
  for (int off = 1; off < 64; off <<= 1) {
    int y = __shfl_up(incl, off);
    if (lane >= off) incl += y;
  }
  __shared__ int ws[4];
  if (lane == 63) ws[wid] = incl;
  __syncthreads();
  int wbase = 0;
#pragma unroll
  for (int w = 0; w < 4; ++w) if (w < wid) wbase += ws[w];
  int off0 = pbase + wbase + (incl - tsum);
  int4 ov;
  ov.x = off0;
  ov.y = off0 + c.x;
  ov.z = off0 + c.x + c.y;
  ov.w = off0 + c.x + c.y + c.z;
  float4 dv;
  dv.x = rsqrtf((float)(c.x + 1));
  dv.y = rsqrtf((float)(c.y + 1));
  dv.z = rsqrtf((float)(c.z + 1));
  dv.w = rsqrtf((float)(c.w + 1));
  if (base + 3 < n) {
    *(int4*)(offs + base) = ov;
    *(int4*)(cur + base) = ov;
    *(float4*)(dinv + base) = dv;
  } else {
    int o4[4] = {ov.x, ov.y, ov.z, ov.w};
    float d4[4] = {dv.x, dv.y, dv.z, dv.w};
    for (int i = 0; i < 4; ++i)
      if (base + i < n) { offs[base + i] = o4[i]; cur[base + i] = o4[i]; dinv[base + i] = d4[i]; }
  }
  if (blockIdx.x == 0 && tid == 0) offs[n] = E;
}

__global__ void fill_adj(const int* __restrict__ src, const int* __restrict__ dst,
                         int* __restrict__ cur, int* __restrict__ adj, int E) {
  int e = blockIdx.x * 256 + threadIdx.x;
  if (e >= E) return;
  int pos = atomicAdd(&cur[dst[e]], 1);
  adj[pos] = src[e];
}

// ---------------- GEMMs ----------------

// C[M][256] bf16 (pre-scaled by dinv[row]) = A[M][512] fp32 x W1t[256][512] bf16
// 128M x 128N tile, grid (M/128, 2) = 782 blocks (~3/CU, balanced), 256 threads (2x2 waves of 64x64).
// A: reg-staged fp32->bf16 (16 floats/thread); B: glds16. Double-buffered, BK=32.
__global__ __launch_bounds__(256) void gemm1_rs(const float* __restrict__ A,
                                                const ushort* __restrict__ Bt,
                                                const float* __restrict__ dinv,
                                                ushort* __restrict__ C, int M) {
  __shared__ __align__(16) ushort As[2][128 * 32];
  __shared__ __align__(16) ushort Bs[2][128 * 32];
  int tid = threadIdx.x;
  int lane = tid & 63, wid = tid >> 6;
  int m0 = blockIdx.x * 128;
  int n0 = blockIdx.y * 128;
  // A staging: row = tid>>1 (0..127), 16 floats at col (tid&1)*16
  int arow = tid >> 1, acol = (tid & 1) * 16;
  int gma = m0 + arow; if (gma >= M) gma = M - 1;
  const float* gA = A + (size_t)gma * IN_C + acol;
  // B staging: chunk c -> row c>>2, col (c&3)*8; this thread: c=tid, c=tid+256
  int bcol = (tid & 3) * 8;
  const ushort* gB0 = Bt + (size_t)(n0 + (tid >> 2)) * IN_C + bcol;
  const ushort* gB1 = Bt + (size_t)(n0 + ((tid + 256) >> 2)) * IN_C + bcol;

  int wr = wid >> 1, wc = wid & 1;           // wave tile (wr*64, wc*64)
  int kf = (lane >> 4) * 8, rl = lane & 15;
  f32x4 acc[4][4] = {};

  // prologue: stage t=0
  {
    float4 p0 = ((const float4*)gA)[0];
    float4 p1 = ((const float4*)gA)[1];
    float4 p2 = ((const float4*)gA)[2];
    float4 p3 = ((const float4*)gA)[3];
    glds16(gB0, &Bs[0][tid * 8]);
    glds16(gB1, &Bs[0][(tid + 256) * 8]);
    uint4 w0, w1;
    w0.x = pack2bf(p0.x, p0.y); w0.y = pack2bf(p0.z, p0.w);
    w0.z = pack2bf(p1.x, p1.y); w0.w = pack2bf(p1.z, p1.w);
    w1.x = pack2bf(p2.x, p2.y); w1.y = pack2bf(p2.z, p2.w);
    w1.z = pack2bf(p3.x, p3.y); w1.w = pack2bf(p3.z, p3.w);
    *(uint4*)&As[0][arow * 32 + acol] = w0;
    *(uint4*)&As[0][arow * 32 + acol + 8] = w1;
  }
  __syncthreads();

  int cur = 0;
  for (int t = 0; t < 16; ++t) {
    float4 p0, p1, p2, p3;
    if (t < 15) {
      const float* g = gA + (t + 1) * 32;
      p0 = ((const float4*)g)[0];
      p1 = ((const float4*)g)[1];
      p2 = ((const float4*)g)[2];
      p3 = ((const float4*)g)[3];
      glds16(gB0 + (t + 1) * 32, &Bs[cur ^ 1][tid * 8]);
      glds16(gB1 + (t + 1) * 32, &Bs[cur ^ 1][(tid + 256) * 8]);
    }
    bf16x8 af[4], bfr[4];
#pragma unroll
    for (int i = 0; i < 4; ++i)
      af[i] = *(const bf16x8*)&As[cur][(wr * 64 + i * 16 + rl) * 32 + kf];
#pragma unroll
    for (int j = 0; j < 4; ++j)
      bfr[j] = *(const bf16x8*)&Bs[cur][(wc * 64 + j * 16 + rl) * 32 + kf];
#pragma unroll
    for (int i = 0; i < 4; ++i)
#pragma unroll
      for (int j = 0; j < 4; ++j)
        acc[i][j] = __builtin_amdgcn_mfma_f32_16x16x32_bf16(af[i], bfr[j], acc[i][j], 0, 0, 0);
    if (t < 15) {
      uint4 w0, w1;
      w0.x = pack2bf(p0.x, p0.y); w0.y = pack2bf(p0.z, p0.w);
      w0.z = pack2bf(p1.x, p1.y); w0.w = pack2bf(p1.z, p1.w);
      w1.x = pack2bf(p2.x, p2.y); w1.y = pack2bf(p2.z, p2.w);
      w1.z = pack2bf(p3.x, p3.y); w1.w = pack2bf(p3.z, p3.w);
      *(uint4*)&As[cur ^ 1][arow * 32 + acol] = w0;
      *(uint4*)&As[cur ^ 1][arow * 32 + acol + 8] = w1;
    }
    __syncthreads();
    cur ^= 1;
  }

  int r4 = (lane >> 4) * 4;
  int cl = lane & 15;
#pragma unroll
  for (int i = 0; i < 4; ++i) {
#pragma unroll
    for (int r = 0; r < 4; ++r) {
      int gr = m0 + wr * 64 + i * 16 + r4 + r;
      if (gr < M) {
        float dv = dinv[gr];
#pragma unroll
        for (int j = 0; j < 4; ++j) {
          int gc = n0 + wc * 64 + j * 16 + cl;
          C[(size_t)gr * HID_C + gc] = f2bf(dv * acc[i][j][r]);
        }
      }
    }
  }
}

// C[M][64] bf16 (pre-scaled) = A[M][256] bf16 x W2t[64][256] bf16
// 64M x 64N tile, 256 threads (4 waves of 16x64), BK=32, double-buffered glds16.
__global__ __launch_bounds__(256) void gemm2(const ushort* __restrict__ A,
                                             const ushort* __restrict__ Bt,
                                             const float* __restrict__ dinv,
                                             ushort* __restrict__ C, int M) {
  __shared__ __align__(16) ushort As[2][64 * 32];
  __shared__ __align__(16) ushort Bs[2][64 * 32];
  int tid = threadIdx.x;
  int lane = tid & 63, wid = tid >> 6;
  int m0 = blockIdx.x * 64;
  int arow = tid >> 2, acol = (tid & 3) * 8;
  int gma = m0 + arow; if (gma >= M) gma = M - 1;
  const ushort* gA = A + (size_t)gma * HID_C + acol;
  const ushort* gB = Bt + (size_t)arow * HID_C + acol;

  int wm = wid * 16;
  int kf = (lane >> 4) * 8, rl = lane & 15;
  f32x4 acc[4] = {};

  glds16(gA, &As[0][tid * 8]);
  glds16(gB, &Bs[0][tid * 8]);
  __syncthreads();

  int cur = 0;
  for (int t = 0; t < 8; ++t) {
    if (t < 7) {
      int k0 = (t + 1) * 32;
      glds16(gA + k0, &As[cur ^ 1][tid * 8]);
      glds16(gB + k0, &Bs[cur ^ 1][tid * 8]);
    }
    bf16x8 a, b[4];
    a = *(const bf16x8*)&As[cur][(wm + rl) * 32 + kf];
#pragma unroll
    for (int j = 0; j < 4; ++j)
      b[j] = *(const bf16x8*)&Bs[cur][(j * 16 + rl) * 32 + kf];
#pragma unroll
    for (int j = 0; j < 4; ++j)
      acc[j] = __builtin_amdgcn_mfma_f32_16x16x32_bf16(a, b[j], acc[j], 0, 0, 0);
    __syncthreads();
    cur ^= 1;
  }

  int r4 = (lane >> 4) * 4;
  int cl = lane & 15;
#pragma unroll
  for (int r = 0; r < 4; ++r) {
    int gr = m0 + wm + r4 + r;
    if (gr < M) {
      float dv = dinv[gr];
#pragma unroll
      for (int j = 0; j < 4; ++j) {
        int gc = j * 16 + cl;
        C[(size_t)gr * OUT_C + gc] = f2bf(dv * acc[j][r]);
      }
    }
  }
}

// ---------------- aggregation ----------------

// one wave per node; adj batch preloaded by all 64 lanes, broadcast via shfl.
// WAVE-UNIFORM trip count; accumulate predicated by k < bn.
__global__ __launch_bounds__(256) void agg1(const ushort* __restrict__ h,
                                            ushort* __restrict__ out,
                                            const float* __restrict__ dinv,
                                            const int* __restrict__ offs,
                                            const int* __restrict__ adj,
                                            const float* __restrict__ bias, int Nn) {
  int node = blockIdx.x * 4 + (threadIdx.x >> 6);
  if (node >= Nn) return;
  int lane = threadIdx.x & 63;
  int slot = lane >> 4;
  int c0 = (lane & 15) * 16;
  int e0 = offs[node];
  int cnt = offs[node + 1] - e0 + 1;  // virtual edge 0 = self
  const ushort* hc = h + c0;
  f32x2 aLo[4] = {}, aHi[4] = {};
  for (int b0 = 0; b0 < cnt; b0 += 64) {
    int vk = b0 + lane;
    int myadj = node;
    if (vk > 0 && vk < cnt) myadj = adj[e0 + vk - 1];
    int bn = cnt - b0; if (bn > 64) bn = 64;
    int iters = (bn + 3) >> 2;  // uniform across the wave
#pragma unroll 4
    for (int i = 0; i < iters; ++i) {
      int k = slot + 4 * i;
      int s = __shfl(myadj, k < bn ? k : 0);
      if (k < bn) {
        const uint4* rp = (const uint4*)(hc + (size_t)s * HID_C);
        uint4 u0 = rp[0];
        uint4 u1 = rp[1];
        pkacc(aLo[0], aHi[0], u0.x, u0.y);
        pkacc(aLo[1], aHi[1], u0.z, u0.w);
        pkacc(aLo[2], aHi[2], u1.x, u1.y);
        pkacc(aLo[3], aHi[3], u1.z, u1.w);
      }
    }
  }
  float r16[16];
#pragma unroll
  for (int q = 0; q < 4; ++q) {
    r16[4 * q + 0] = aLo[q][0];
    r16[4 * q + 1] = aHi[q][0];
    r16[4 * q + 2] = aLo[q][1];
    r16[4 * q + 3] = aHi[q][1];
  }
#pragma unroll
  for (int i = 0; i < 16; ++i) {
    r16[i] += __shfl_xor(r16[i], 16);
    r16[i] += __shfl_xor(r16[i], 32);
  }
  if (lane < 16) {
    float dv = dinv[node];
    const float4* bp = (const float4*)(bias + c0);
    float bb[16];
#pragma unroll
    for (int q = 0; q < 4; ++q) {
      float4 b4 = bp[q];
      bb[q * 4 + 0] = b4.x; bb[q * 4 + 1] = b4.y;
      bb[q * 4 + 2] = b4.z; bb[q * 4 + 3] = b4.w;
    }
    uint r[8];
#pragma unroll
    for (int i = 0; i < 8; ++i) {
      float v0 = fmaxf(dv * r16[2 * i]     + bb[2 * i],     0.f);
      float v1 = fmaxf(dv * r16[2 * i + 1] + bb[2 * i + 1], 0.f);
      r[i] = (uint)f2bf(v0) | ((uint)f2bf(v1) << 16);
    }
    uint4* op = (uint4*)(out + (size_t)node * HID_C + c0);
    op[0] = make_uint4(r[0], r[1], r[2], r[3]);
    op[1] = make_uint4(r[4], r[5], r[6], r[7]);
  }
}

// one wave per node; 8 edge slots x 8 lanes x 16B; uniform trip count.
__global__ __launch_bounds__(256) void agg2(const ushort* __restrict__ h,
                                            float* __restrict__ out,
                                            const float* __restrict__ dinv,
                                            const int* __restrict__ offs,
                                            const int* __restrict__ adj,
                                            const float* __restrict__ bias, int Nn) {
  int node = blockIdx.x * 4 + (threadIdx.x >> 6);
  if (node >= Nn) return;
  int lane = threadIdx.x & 63;
  int slot = lane >> 3;
  int c0 = (lane & 7) * 8;
  int e0 = offs[node];
  int cnt = offs[node + 1] - e0 + 1;
  const ushort* hc = h + c0;
  f32x2 aLo[2] = {}, aHi[2] = {};
  for (int b0 = 0; b0 < cnt; b0 += 64) {
    int vk = b0 + lane;
    int myadj = node;
    if (vk > 0 && vk < cnt) myadj = adj[e0 + vk - 1];
    int bn = cnt - b0; if (bn > 64) bn = 64;
    int iters = (bn + 7) >> 3;  // uniform across the wave
#pragma unroll 4
    for (int i = 0; i < iters; ++i) {
      int k = slot + 8 * i;
      int s = __shfl(myadj, k < bn ? k : 0);
      if (k < bn) {
        uint4 u = *(const uint4*)(hc + (size_t)s * OUT_C);
        pkacc(aLo[0], aHi[0], u.x, u.y);
        pkacc(aLo[1], aHi[1], u.z, u.w);
      }
    }
  }
  float r8[8];
#pragma unroll
  for (int q = 0; q < 2; ++q) {
    r8[4 * q + 0] = aLo[q][0];
    r8[4 * q + 1] = aHi[q][0];
    r8[4 * q + 2] = aLo[q][1];
    r8[4 * q + 3] = aHi[q][1];
  }
#pragma unroll
  for (int i = 0; i < 8; ++i) {
    r8[i] += __shfl_xor(r8[i], 8);
    r8[i] += __shfl_xor(r8[i], 16);
    r8[i] += __shfl_xor(r8[i], 32);
  }
  float dv = dinv[node];
  const float4* bp = (const float4*)(bias + c0);
  float4 bb0 = bp[0], bb1 = bp[1];
  float v[8];
  v[0] = dv * r8[0] + bb0.x; v[1] = dv * r8[1] + bb0.y;
  v[2] = dv * r8[2] + bb0.z; v[3] = dv * r8[3] + bb0.w;
  v[4] = dv * r8[4] + bb1.x; v[5] = dv * r8[5] + bb1.y;
  v[6] = dv * r8[6] + bb1.z; v[7] = dv * r8[7] + bb1.w;
  float m = v[0];
#pragma unroll
  for (int i = 1; i < 8; ++i) m = fmaxf(m, v[i]);
  m = fmaxf(m, __shfl_xor(m, 1));
  m = fmaxf(m, __shfl_xor(m, 2));
  m = fmaxf(m, __shfl_xor(m, 4));
  float s8 = 0.f;
#pragma unroll
  for (int i = 0; i < 8; ++i) s8 += expf(v[i] - m);
  s8 += __shfl_xor(s8, 1);
  s8 += __shfl_xor(s8, 2);
  s8 += __shfl_xor(s8, 4);
  float lg = logf(s8);
  if (lane < 8) {
    float4* op = (float4*)(out + (size_t)node * OUT_C + c0);
    op[0] = make_float4(v[0] - m - lg, v[1] - m - lg, v[2] - m - lg, v[3] - m - lg);
    op[1] = make_float4(v[4] - m - lg, v[5] - m - lg, v[6] - m - lg, v[7] - m - lg);
  }
}

// ---------------- launch ----------------

extern "C" void kernel_launch(void* const* d_in, const int* in_sizes, int n_in,
                              void* d_out, int out_size, void* d_ws, size_t ws_size,
                              hipStream_t stream) {
  const float* x  = (const float*)d_in[0];
  const int*   ei = (const int*)d_in[1];
  const float* W1 = (const float*)d_in[2];
  const float* b1 = (const float*)d_in[3];
  const float* W2 = (const float*)d_in[4];
  const float* b2 = (const float*)d_in[5];
  float* outp = (float*)d_out;

  int Nn = in_sizes[0] / IN_C;
  int E  = in_sizes[1] / 2;
  const int* srcv = ei;
  const int* dstv = ei + E;

  char* ws = (char*)d_ws;
  size_t o = 0;
  auto alloc = [&](size_t bytes) {
    char* p = ws + o;
    o = (o + bytes + 255) & ~(size_t)255;
    return p;
  };
  float*  dinv  = (float*)alloc((size_t)Nn * 4);
  int*    counts= (int*)alloc((size_t)Nn * 4);
  int*    offs  = (int*)alloc((size_t)(Nn + 1) * 4);
  int*    cur   = (int*)alloc((size_t)Nn * 4);
  int*    adj   = (int*)alloc((size_t)E * 4);
  int*    partial=(int*)alloc((size_t)((Nn + SCAN_TILE - 1) / SCAN_TILE) * 4);
  ushort* W1t   = (ushort*)alloc((size_t)IN_C * HID_C * 2);
  ushort* W2t   = (ushort*)alloc((size_t)HID_C * OUT_C * 2);
  ushort* h1p   = (ushort*)alloc((size_t)Nn * HID_C * 2);
  ushort* h1a   = (ushort*)alloc((size_t)Nn * HID_C * 2);
  ushort* h2p   = (ushort*)alloc((size_t)Nn * OUT_C * 2);

  int eb = (E + 255) / 256;
  int sb = (Nn + SCAN_TILE - 1) / SCAN_TILE;

  hipMemsetAsync(counts, 0, (size_t)Nn * 4, stream);
  deg_count_tw<<<eb + 256, 256, 0, stream>>>(dstv, counts, E, eb, W1, W1t, W2, W2t);
  scan_block_sums<<<sb, 256, 0, stream>>>(counts, partial, Nn);
  scan_write<<<sb, 256, 0, stream>>>(counts, partial, offs, cur, dinv, Nn, E, sb);
  fill_adj<<<eb, 256, 0, stream>>>(srcv, dstv, cur, adj, E);

  gemm1_rs<<<dim3((Nn + 127) / 128, 2), 256, 0, stream>>>(x, W1t, dinv, h1p, Nn);
  agg1<<<(Nn + 3) / 4, 256, 0, stream>>>(h1p, h1a, dinv, offs, adj, b1, Nn);
  gemm2<<<(Nn + 63) / 64, 256, 0, stream>>>(h1a, W2t, dinv, h2p, Nn);
  agg2<<<(Nn + 3) / 4, 256, 0, stream>>>(h2p, outp, dinv, offs, adj, b2, Nn);
}

// Round 12
// 225.116 us; speedup vs baseline: 1.0924x; 1.0924x over previous
//
#include <hip/hip_runtime.h>
#include <hip/hip_bf16.h>

#define IN_C 512
#define HID_C 256
#define OUT_C 64

typedef __attribute__((ext_vector_type(8))) short bf16x8;
typedef __attribute__((ext_vector_type(4))) float f32x4;
typedef __attribute__((ext_vector_type(2))) float f32x2;

__device__ __forceinline__ ushort f2bf(float f) {
  __hip_bfloat16 h = __float2bfloat16(f);
  union { __hip_bfloat16 h; ushort u; } v; v.h = h; return v.u;
}
__device__ __forceinline__ uint pack2bf(float a, float b) {
  return (uint)f2bf(a) | ((uint)f2bf(b) << 16);
}
__device__ __forceinline__ float u2f(uint u) {
  union { uint i; float f; } v; v.i = u; return v.f;
}
// packed accumulate of 4 bf16 {lo0,hi0,lo1,hi1} in (ux,uy) — exact bf16 values.
__device__ __forceinline__ void pkacc(f32x2& aLo, f32x2& aHi, uint ux, uint uy) {
  f32x2 lo, hi;
  lo[0] = u2f(ux << 16);         lo[1] = u2f(uy << 16);
  hi[0] = u2f(ux & 0xffff0000u); hi[1] = u2f(uy & 0xffff0000u);
  aLo += lo;   // v_pk_add_f32
  aHi += hi;
}
// async global->LDS, 16B per lane. LDS dest must be linear (base + lane*16).
__device__ __forceinline__ void glds16(const ushort* g, ushort* l) {
  __builtin_amdgcn_global_load_lds(
      (const __attribute__((address_space(1))) unsigned int*)(const void*)g,
      (__attribute__((address_space(3))) unsigned int*)(void*)l, 16, 0, 0);
}

// ---------------- graph preprocessing ----------------

// edges blocks: deg count atomics. Extra 256 blocks: W1/W2 transpose (fp32 -> bf16, n-major).
__global__ void deg_count_tw(const int* __restrict__ dst, int* __restrict__ counts, int E, int eb,
                             const float* __restrict__ W1, ushort* __restrict__ W1t,
                             const float* __restrict__ W2, ushort* __restrict__ W2t) {
  if ((int)blockIdx.x < eb) {
    int e = blockIdx.x * 256 + threadIdx.x;
    if (e < E) atomicAdd(&counts[dst[e]], 1);
    return;
  }
  int b2 = blockIdx.x - eb;
  int z = b2 >> 7;        // 0: W1, 1: W2
  int rem = b2 & 127;
  int bx = rem & 7, by = rem >> 3;
  const float* W; ushort* Wt; int K, N;
  if (z == 0) { W = W1; Wt = W1t; K = IN_C; N = HID_C; }
  else        { W = W2; Wt = W2t; K = HID_C; N = OUT_C; }
  int n0 = bx * 32, k0 = by * 32;
  if (n0 >= N || k0 >= K) return;
  __shared__ ushort t[32][33];
  int tx = threadIdx.x & 31;
  int ty = threadIdx.x >> 5;  // 0..7
#pragma unroll
  for (int i = 0; i < 4; ++i) {
    int k = k0 + ty + i * 8;
    t[ty + i * 8][tx] = f2bf(W[(size_t)k * N + n0 + tx]);
  }
  __syncthreads();
#pragma unroll
  for (int i = 0; i < 4; ++i) {
    int n = n0 + ty + i * 8;
    Wt[(size_t)n * K + k0 + tx] = t[tx][ty + i * 8];
  }
}

#define SCAN_TILE 1024

__global__ __launch_bounds__(256) void scan_block_sums(const int* __restrict__ counts,
                                                       int* __restrict__ partial, int n) {
  int base = blockIdx.x * SCAN_TILE + threadIdx.x * 4;
  int s = 0;
  if (base + 3 < n) {
    int4 v = *(const int4*)(counts + base);
    s = v.x + v.y + v.z + v.w;
  } else {
#pragma unroll
    for (int i = 0; i < 4; ++i) if (base + i < n) s += counts[base + i];
  }
#pragma unroll
  for (int off = 1; off < 64; off <<= 1) s += __shfl_xor(s, off);
  __shared__ int ws[4];
  int lane = threadIdx.x & 63, wid = threadIdx.x >> 6;
  if (lane == 0) ws[wid] = s;
  __syncthreads();
  if (threadIdx.x == 0) partial[blockIdx.x] = ws[0] + ws[1] + ws[2] + ws[3];
}

// intra-block exclusive scan; block base = sum of partial[0..bid-1] (nb<=64, one wave).
__global__ __launch_bounds__(256) void scan_write(const int* __restrict__ counts,
                                                  const int* __restrict__ partial,
                                                  int* __restrict__ offs,
                                                  int* __restrict__ cur,
                                                  float* __restrict__ dinv,
                                                  int n, int E, int nb) {
  __shared__ int sbase;
  int tid = threadIdx.x;
  if (tid < 64) {
    int v = (tid < (int)blockIdx.x && tid < nb) ? partial[tid] : 0;
#pragma unroll
    for (int off = 1; off < 64; off <<= 1) v += __shfl_xor(v, off);
    if (tid == 0) sbase = v;
  }
  __syncthreads();
  int pbase = sbase;
  int base = blockIdx.x * SCAN_TILE + tid * 4;
  int4 c = make_int4(0, 0, 0, 0);
  if (base + 3 < n) {
    c = *(const int4*)(counts + base);
  } else {
    if (base + 0 < n) c.x = counts[base + 0];
    if (base + 1 < n) c.y = counts[base + 1];
    if (base + 2 < n) c.z = counts[base + 2];
  }
  int tsum = c.x + c.y + c.z + c.w;
  int lane = tid & 63, wid = tid >> 6;
  int incl = tsum;
#pragma unroll
  for (int off = 1; off < 64; off <<= 1) {
    int y = __shfl_up(incl, off);
    if (lane >= off) incl += y;
  }
  __shared__ int ws[4];
  if (lane == 63) ws[wid] = incl;
  __syncthreads();
  int wbase = 0;
#pragma unroll
  for (int w = 0; w < 4; ++w) if (w < wid) wbase += ws[w];
  int off0 = pbase + wbase + (incl - tsum);
  int4 ov;
  ov.x = off0;
  ov.y = off0 + c.x;
  ov.z = off0 + c.x + c.y;
  ov.w = off0 + c.x + c.y + c.z;
  float4 dv;
  dv.x = rsqrtf((float)(c.x + 1));
  dv.y = rsqrtf((float)(c.y + 1));
  dv.z = rsqrtf((float)(c.z + 1));
  dv.w = rsqrtf((float)(c.w + 1));
  if (base + 3 < n) {
    *(int4*)(offs + base) = ov;
    *(int4*)(cur + base) = ov;
    *(float4*)(dinv + base) = dv;
  } else {
    int o4[4] = {ov.x, ov.y, ov.z, ov.w};
    float d4[4] = {dv.x, dv.y, dv.z, dv.w};
    for (int i = 0; i < 4; ++i)
      if (base + i < n) { offs[base + i] = o4[i]; cur[base + i] = o4[i]; dinv[base + i] = d4[i]; }
  }
  if (blockIdx.x == 0 && tid == 0) offs[n] = E;
}

__global__ void fill_adj(const int* __restrict__ src, const int* __restrict__ dst,
                         int* __restrict__ cur, int* __restrict__ adj, int E) {
  int e = blockIdx.x * 256 + threadIdx.x;
  if (e >= E) return;
  int pos = atomicAdd(&cur[dst[e]], 1);
  adj[pos] = src[e];
}

// ---------------- GEMMs ----------------

// C[M][256] bf16 (pre-scaled by dinv[row]) = A[M][512] fp32 x W1t[256][512] bf16
// Single N-tile (128M x 256N), 512 threads (2x4 waves of 64x64), BK=32.
// A: reg-staged fp32->bf16; B: glds16. Double-buffered. (Best of 4 measured variants.)
__global__ __launch_bounds__(512) void gemm1_fs(const float* __restrict__ A,
                                                const ushort* __restrict__ Bt,
                                                const float* __restrict__ dinv,
                                                ushort* __restrict__ C, int M) {
  __shared__ __align__(16) ushort As[2][128 * 32];
  __shared__ __align__(16) ushort Bs[2][256 * 32];
  int tid = threadIdx.x;
  int lane = tid & 63, wid = tid >> 6;       // wid 0..7
  int m0 = blockIdx.x * 128;
  int arow = tid >> 2, acol = (tid & 3) * 8;
  int gma = m0 + arow; if (gma >= M) gma = M - 1;
  const float* gA = A + (size_t)gma * IN_C + acol;
  int rb0 = tid >> 2, cb0 = (tid & 3) * 8;
  int rb1 = (tid + 512) >> 2;
  const ushort* gB0 = Bt + (size_t)rb0 * IN_C + cb0;
  const ushort* gB1 = Bt + (size_t)rb1 * IN_C + cb0;

  int wr = wid >> 2, wc = wid & 3;           // wave tile (wr*64, wc*64)
  int kf = (lane >> 4) * 8, rl = lane & 15;
  f32x4 acc[4][4] = {};

  // prologue: stage t=0
  {
    float4 p0 = *(const float4*)gA;
    float4 p1 = *(const float4*)(gA + 4);
    glds16(gB0, &Bs[0][tid * 8]);
    glds16(gB1, &Bs[0][(tid + 512) * 8]);
    uint4 w;
    w.x = pack2bf(p0.x, p0.y); w.y = pack2bf(p0.z, p0.w);
    w.z = pack2bf(p1.x, p1.y); w.w = pack2bf(p1.z, p1.w);
    *(uint4*)&As[0][arow * 32 + acol] = w;
  }
  __syncthreads();

  int cur = 0;
  for (int t = 0; t < 16; ++t) {
    float4 p0, p1;
    if (t < 15) {
      const float* g = gA + (t + 1) * 32;
      p0 = *(const float4*)g;
      p1 = *(const float4*)(g + 4);
      glds16(gB0 + (t + 1) * 32, &Bs[cur ^ 1][tid * 8]);
      glds16(gB1 + (t + 1) * 32, &Bs[cur ^ 1][(tid + 512) * 8]);
    }
    bf16x8 af[4], bf[4];
#pragma unroll
    for (int i = 0; i < 4; ++i)
      af[i] = *(const bf16x8*)&As[cur][(wr * 64 + i * 16 + rl) * 32 + kf];
#pragma unroll
    for (int j = 0; j < 4; ++j)
      bf[j] = *(const bf16x8*)&Bs[cur][(wc * 64 + j * 16 + rl) * 32 + kf];
#pragma unroll
    for (int i = 0; i < 4; ++i)
#pragma unroll
      for (int j = 0; j < 4; ++j)
        acc[i][j] = __builtin_amdgcn_mfma_f32_16x16x32_bf16(af[i], bf[j], acc[i][j], 0, 0, 0);
    if (t < 15) {
      uint4 w;
      w.x = pack2bf(p0.x, p0.y); w.y = pack2bf(p0.z, p0.w);
      w.z = pack2bf(p1.x, p1.y); w.w = pack2bf(p1.z, p1.w);
      *(uint4*)&As[cur ^ 1][arow * 32 + acol] = w;
    }
    __syncthreads();
    cur ^= 1;
  }

  int r4 = (lane >> 4) * 4;
  int cl = lane & 15;
#pragma unroll
  for (int i = 0; i < 4; ++i) {
#pragma unroll
    for (int r = 0; r < 4; ++r) {
      int gr = m0 + wr * 64 + i * 16 + r4 + r;
      if (gr < M) {
        float dv = dinv[gr];
#pragma unroll
        for (int j = 0; j < 4; ++j) {
          int gc = wc * 64 + j * 16 + cl;
          C[(size_t)gr * HID_C + gc] = f2bf(dv * acc[i][j][r]);
        }
      }
    }
  }
}

// C[M][64] bf16 (pre-scaled) = A[M][256] bf16 x W2t[64][256] bf16
// 64M x 64N tile, 256 threads (4 waves of 16x64), BK=32, double-buffered glds16.
__global__ __launch_bounds__(256) void gemm2(const ushort* __restrict__ A,
                                             const ushort* __restrict__ Bt,
                                             const float* __restrict__ dinv,
                                             ushort* __restrict__ C, int M) {
  __shared__ __align__(16) ushort As[2][64 * 32];
  __shared__ __align__(16) ushort Bs[2][64 * 32];
  int tid = threadIdx.x;
  int lane = tid & 63, wid = tid >> 6;
  int m0 = blockIdx.x * 64;
  int arow = tid >> 2, acol = (tid & 3) * 8;
  int gma = m0 + arow; if (gma >= M) gma = M - 1;
  const ushort* gA = A + (size_t)gma * HID_C + acol;
  const ushort* gB = Bt + (size_t)arow * HID_C + acol;

  int wm = wid * 16;
  int kf = (lane >> 4) * 8, rl = lane & 15;
  f32x4 acc[4] = {};

  glds16(gA, &As[0][tid * 8]);
  glds16(gB, &Bs[0][tid * 8]);
  __syncthreads();

  int cur = 0;
  for (int t = 0; t < 8; ++t) {
    if (t < 7) {
      int k0 = (t + 1) * 32;
      glds16(gA + k0, &As[cur ^ 1][tid * 8]);
      glds16(gB + k0, &Bs[cur ^ 1][tid * 8]);
    }
    bf16x8 a, b[4];
    a = *(const bf16x8*)&As[cur][(wm + rl) * 32 + kf];
#pragma unroll
    for (int j = 0; j < 4; ++j)
      b[j] = *(const bf16x8*)&Bs[cur][(j * 16 + rl) * 32 + kf];
#pragma unroll
    for (int j = 0; j < 4; ++j)
      acc[j] = __builtin_amdgcn_mfma_f32_16x16x32_bf16(a, b[j], acc[j], 0, 0, 0);
    __syncthreads();
    cur ^= 1;
  }

  int r4 = (lane >> 4) * 4;
  int cl = lane & 15;
#pragma unroll
  for (int r = 0; r < 4; ++r) {
    int gr = m0 + wm + r4 + r;
    if (gr < M) {
      float dv = dinv[gr];
#pragma unroll
      for (int j = 0; j < 4; ++j) {
        int gc = j * 16 + cl;
        C[(size_t)gr * OUT_C + gc] = f2bf(dv * acc[j][r]);
      }
    }
  }
}

// ---------------- aggregation ----------------

// one wave per node; adj batch preloaded by all 64 lanes, broadcast via shfl.
// WAVE-UNIFORM trip count; accumulate predicated by k < bn.
__global__ __launch_bounds__(256) void agg1(const ushort* __restrict__ h,
                                            ushort* __restrict__ out,
                                            const float* __restrict__ dinv,
                                            const int* __restrict__ offs,
                                            const int* __restrict__ adj,
                                            const float* __restrict__ bias, int Nn) {
  int node = blockIdx.x * 4 + (threadIdx.x >> 6);
  if (node >= Nn) return;
  int lane = threadIdx.x & 63;
  int slot = lane >> 4;
  int c0 = (lane & 15) * 16;
  int e0 = offs[node];
  int cnt = offs[node + 1] - e0 + 1;  // virtual edge 0 = self
  const ushort* hc = h + c0;
  f32x2 aLo[4] = {}, aHi[4] = {};
  for (int b0 = 0; b0 < cnt; b0 += 64) {
    int vk = b0 + lane;
    int myadj = node;
    if (vk > 0 && vk < cnt) myadj = adj[e0 + vk - 1];
    int bn = cnt - b0; if (bn > 64) bn = 64;
    int iters = (bn + 3) >> 2;  // uniform across the wave
#pragma unroll 4
    for (int i = 0; i < iters; ++i) {
      int k = slot + 4 * i;
      int s = __shfl(myadj, k < bn ? k : 0);
      if (k < bn) {
        const uint4* rp = (const uint4*)(hc + (size_t)s * HID_C);
        uint4 u0 = rp[0];
        uint4 u1 = rp[1];
        pkacc(aLo[0], aHi[0], u0.x, u0.y);
        pkacc(aLo[1], aHi[1], u0.z, u0.w);
        pkacc(aLo[2], aHi[2], u1.x, u1.y);
        pkacc(aLo[3], aHi[3], u1.z, u1.w);
      }
    }
  }
  float r16[16];
#pragma unroll
  for (int q = 0; q < 4; ++q) {
    r16[4 * q + 0] = aLo[q][0];
    r16[4 * q + 1] = aHi[q][0];
    r16[4 * q + 2] = aLo[q][1];
    r16[4 * q + 3] = aHi[q][1];
  }
#pragma unroll
  for (int i = 0; i < 16; ++i) {
    r16[i] += __shfl_xor(r16[i], 16);
    r16[i] += __shfl_xor(r16[i], 32);
  }
  if (lane < 16) {
    float dv = dinv[node];
    const float4* bp = (const float4*)(bias + c0);
    float bb[16];
#pragma unroll
    for (int q = 0; q < 4; ++q) {
      float4 b4 = bp[q];
      bb[q * 4 + 0] = b4.x; bb[q * 4 + 1] = b4.y;
      bb[q * 4 + 2] = b4.z; bb[q * 4 + 3] = b4.w;
    }
    uint r[8];
#pragma unroll
    for (int i = 0; i < 8; ++i) {
      float v0 = fmaxf(dv * r16[2 * i]     + bb[2 * i],     0.f);
      float v1 = fmaxf(dv * r16[2 * i + 1] + bb[2 * i + 1], 0.f);
      r[i] = (uint)f2bf(v0) | ((uint)f2bf(v1) << 16);
    }
    uint4* op = (uint4*)(out + (size_t)node * HID_C + c0);
    op[0] = make_uint4(r[0], r[1], r[2], r[3]);
    op[1] = make_uint4(r[4], r[5], r[6], r[7]);
  }
}

// one wave per node; 8 edge slots x 8 lanes x 16B; uniform trip count.
__global__ __launch_bounds__(256) void agg2(const ushort* __restrict__ h,
                                            float* __restrict__ out,
                                            const float* __restrict__ dinv,
                                            const int* __restrict__ offs,
                                            const int* __restrict__ adj,
                                            const float* __restrict__ bias, int Nn) {
  int node = blockIdx.x * 4 + (threadIdx.x >> 6);
  if (node >= Nn) return;
  int lane = threadIdx.x & 63;
  int slot = lane >> 3;
  int c0 = (lane & 7) * 8;
  int e0 = offs[node];
  int cnt = offs[node + 1] - e0 + 1;
  const ushort* hc = h + c0;
  f32x2 aLo[2] = {}, aHi[2] = {};
  for (int b0 = 0; b0 < cnt; b0 += 64) {
    int vk = b0 + lane;
    int myadj = node;
    if (vk > 0 && vk < cnt) myadj = adj[e0 + vk - 1];
    int bn = cnt - b0; if (bn > 64) bn = 64;
    int iters = (bn + 7) >> 3;  // uniform across the wave
#pragma unroll 4
    for (int i = 0; i < iters; ++i) {
      int k = slot + 8 * i;
      int s = __shfl(myadj, k < bn ? k : 0);
      if (k < bn) {
        uint4 u = *(const uint4*)(hc + (size_t)s * OUT_C);
        pkacc(aLo[0], aHi[0], u.x, u.y);
        pkacc(aLo[1], aHi[1], u.z, u.w);
      }
    }
  }
  float r8[8];
#pragma unroll
  for (int q = 0; q < 2; ++q) {
    r8[4 * q + 0] = aLo[q][0];
    r8[4 * q + 1] = aHi[q][0];
    r8[4 * q + 2] = aLo[q][1];
    r8[4 * q + 3] = aHi[q][1];
  }
#pragma unroll
  for (int i = 0; i < 8; ++i) {
    r8[i] += __shfl_xor(r8[i], 8);
    r8[i] += __shfl_xor(r8[i], 16);
    r8[i] += __shfl_xor(r8[i], 32);
  }
  float dv = dinv[node];
  const float4* bp = (const float4*)(bias + c0);
  float4 bb0 = bp[0], bb1 = bp[1];
  float v[8];
  v[0] = dv * r8[0] + bb0.x; v[1] = dv * r8[1] + bb0.y;
  v[2] = dv * r8[2] + bb0.z; v[3] = dv * r8[3] + bb0.w;
  v[4] = dv * r8[4] + bb1.x; v[5] = dv * r8[5] + bb1.y;
  v[6] = dv * r8[6] + bb1.z; v[7] = dv * r8[7] + bb1.w;
  float m = v[0];
#pragma unroll
  for (int i = 1; i < 8; ++i) m = fmaxf(m, v[i]);
  m = fmaxf(m, __shfl_xor(m, 1));
  m = fmaxf(m, __shfl_xor(m, 2));
  m = fmaxf(m, __shfl_xor(m, 4));
  float s8 = 0.f;
#pragma unroll
  for (int i = 0; i < 8; ++i) s8 += expf(v[i] - m);
  s8 += __shfl_xor(s8, 1);
  s8 += __shfl_xor(s8, 2);
  s8 += __shfl_xor(s8, 4);
  float lg = logf(s8);
  if (lane < 8) {
    float4* op = (float4*)(out + (size_t)node * OUT_C + c0);
    op[0] = make_float4(v[0] - m - lg, v[1] - m - lg, v[2] - m - lg, v[3] - m - lg);
    op[1] = make_float4(v[4] - m - lg, v[5] - m - lg, v[6] - m - lg, v[7] - m - lg);
  }
}

// ---------------- launch ----------------

extern "C" void kernel_launch(void* const* d_in, const int* in_sizes, int n_in,
                              void* d_out, int out_size, void* d_ws, size_t ws_size,
                              hipStream_t stream) {
  const float* x  = (const float*)d_in[0];
  const int*   ei = (const int*)d_in[1];
  const float* W1 = (const float*)d_in[2];
  const float* b1 = (const float*)d_in[3];
  const float* W2 = (const float*)d_in[4];
  const float* b2 = (const float*)d_in[5];
  float* outp = (float*)d_out;

  int Nn = in_sizes[0] / IN_C;
  int E  = in_sizes[1] / 2;
  const int* srcv = ei;
  const int* dstv = ei + E;

  char* ws = (char*)d_ws;
  size_t o = 0;
  auto alloc = [&](size_t bytes) {
    char* p = ws + o;
    o = (o + bytes + 255) & ~(size_t)255;
    return p;
  };
  float*  dinv  = (float*)alloc((size_t)Nn * 4);
  int*    counts= (int*)alloc((size_t)Nn * 4);
  int*    offs  = (int*)alloc((size_t)(Nn + 1) * 4);
  int*    cur   = (int*)alloc((size_t)Nn * 4);
  int*    adj   = (int*)alloc((size_t)E * 4);
  int*    partial=(int*)alloc((size_t)((Nn + SCAN_TILE - 1) / SCAN_TILE) * 4);
  ushort* W1t   = (ushort*)alloc((size_t)IN_C * HID_C * 2);
  ushort* W2t   = (ushort*)alloc((size_t)HID_C * OUT_C * 2);
  ushort* h1p   = (ushort*)alloc((size_t)Nn * HID_C * 2);
  ushort* h1a   = (ushort*)alloc((size_t)Nn * HID_C * 2);
  ushort* h2p   = (ushort*)alloc((size_t)Nn * OUT_C * 2);

  int eb = (E + 255) / 256;
  int sb = (Nn + SCAN_TILE - 1) / SCAN_TILE;

  hipMemsetAsync(counts, 0, (size_t)Nn * 4, stream);
  deg_count_tw<<<eb + 256, 256, 0, stream>>>(dstv, counts, E, eb, W1, W1t, W2, W2t);
  scan_block_sums<<<sb, 256, 0, stream>>>(counts, partial, Nn);
  scan_write<<<sb, 256, 0, stream>>>(counts, partial, offs, cur, dinv, Nn, E, sb);
  fill_adj<<<eb, 256, 0, stream>>>(srcv, dstv, cur, adj, E);

  gemm1_fs<<<(Nn + 127) / 128, 512, 0, stream>>>(x, W1t, dinv, h1p, Nn);
  agg1<<<(Nn + 3) / 4, 256, 0, stream>>>(h1p, h1a, dinv, offs, adj, b1, Nn);
  gemm2<<<(Nn + 63) / 64, 256, 0, stream>>>(h1a, W2t, dinv, h2p, Nn);
  agg2<<<(Nn + 3) / 4, 256, 0, stream>>>(h2p, outp, dinv, offs, adj, b2, Nn);
}